// Round 17
// baseline (1310.368 us; speedup 1.0000x reference)
//
#include <hip/hip_runtime.h>
#include <hip/hip_bf16.h>
#include <math.h>

#define N_NODES 20000
#define N_EDGES 320000
#define NGRAPH 64
#define EDGE_TILES (N_EDGES/32)
#define EDGE_BLOCKS 2500

typedef __attribute__((ext_vector_type(8))) short short8;
typedef __attribute__((ext_vector_type(4))) short short4x;
typedef __attribute__((ext_vector_type(4))) float f32x4;
typedef __attribute__((ext_vector_type(4))) unsigned uint4v;
typedef __attribute__((ext_vector_type(2))) unsigned uint2v;

// fast silu: hardware v_rcp_f32 instead of IEEE division
__device__ __forceinline__ float silu_f(float v){
  return v * __builtin_amdgcn_rcpf(1.0f + __expf(-v));
}
__device__ __forceinline__ float bf2f(short s){
  unsigned u = ((unsigned)(unsigned short)s) << 16;
  float f; __builtin_memcpy(&f, &u, 4); return f;
}
__device__ __forceinline__ short f2bf(float f){
  unsigned u; __builtin_memcpy(&u, &f, 4);
  unsigned r = (u + 0x7FFFu + ((u >> 16) & 1u)) >> 16;
  return (short)r;
}
__device__ __forceinline__ unsigned pkcvt(float lo, float hi){
  unsigned r;
  asm("v_cvt_pk_bf16_f32 %0, %1, %2" : "=v"(r) : "v"(lo), "v"(hi));
  return r;
}
__device__ __forceinline__ float bf_lo(unsigned w){
  unsigned u = w << 16; float f; __builtin_memcpy(&f, &u, 4); return f;
}
__device__ __forceinline__ float bf_hi(unsigned w){
  unsigned u = w & 0xFFFF0000u; float f; __builtin_memcpy(&f, &u, 4); return f;
}

// ---------------- CSR build: histogram, scan, scatter ----------------
__global__ void k_hist(const int* __restrict__ ei, int* __restrict__ cnt){
  int e = blockIdx.x*256 + threadIdx.x;
  if (e >= N_EDGES) return;
  atomicAdd(&cnt[ei[N_EDGES + e]], 1);
}

__global__ void k_scan(const int* __restrict__ cnt, int* __restrict__ row_ptr,
                       int* __restrict__ off){
  __shared__ int ssum[256];
  int t = threadIdx.x;
  const int CHK = (N_NODES + 255)/256;
  int base = t*CHK;
  int s = 0;
  for(int i=0;i<CHK;i++){ int idx=base+i; if(idx<N_NODES) s += cnt[idx]; }
  ssum[t]=s; __syncthreads();
  for(int o=1;o<256;o<<=1){
    int v = (t>=o)? ssum[t-o] : 0;
    __syncthreads();
    ssum[t] += v;
    __syncthreads();
  }
  int pre = (t==0)? 0 : ssum[t-1];
  for(int i=0;i<CHK;i++){
    int idx=base+i; if(idx>=N_NODES) break;
    row_ptr[idx]=pre; off[idx]=pre; pre += cnt[idx];
  }
  if(t==255) row_ptr[N_NODES]=pre;
}

__global__ void k_scatter(const int* __restrict__ ei, int* __restrict__ off,
                          int* __restrict__ src_s, int* __restrict__ dst_s,
                          int* __restrict__ eid_s){
  int e = blockIdx.x*256 + threadIdx.x;
  if (e >= N_EDGES) return;
  int d = ei[N_EDGES + e];
  int p = atomicAdd(&off[d], 1);
  dst_s[p]=d; src_s[p]=ei[e]; eid_s[p]=e;
}

// ---------------- edge distance (sorted order) ----------------
__global__ void k_dist_s(const int* __restrict__ src_s, const int* __restrict__ dst_s,
                         const float* __restrict__ pos, float* __restrict__ dist_s){
  int i = blockIdx.x*256 + threadIdx.x;
  if (i >= N_EDGES) return;
  int s = src_s[i], d = dst_s[i];
  float dx = pos[s*3+0]-pos[d*3+0];
  float dy = pos[s*3+1]-pos[d*3+1];
  float dz = pos[s*3+2]-pos[d*3+2];
  dist_s[i] = sqrtf(dx*dx+dy*dy+dz*dz);
}

// ---------------- EA_aug via CSR: per-dst sum of edge_attr, count, zeros (stride 96) ----
__global__ void k_eaagg_s(const int* __restrict__ row_ptr, const int* __restrict__ eid_s,
                          const float* __restrict__ edge_attr, float* __restrict__ EA){
  int sub = threadIdx.x>>6, j = threadIdx.x&63;
  int d = blockIdx.x*4 + sub;
  if (d >= N_NODES) return;
  int b = row_ptr[d], e = row_ptr[d+1];
  float s = 0.f;
  for(int i=b;i<e;i++) s += edge_attr[(size_t)eid_s[i]*64 + j];
  EA[(size_t)d*96 + j] = s;
  if (j < 32) EA[(size_t)d*96 + 64 + j] = (j==0) ? (float)(e-b) : 0.f;
}

// ---------------- fp32 -> bf16 convert ----------------
__global__ void k_f2b(const float* __restrict__ S, short* __restrict__ D, int n4){
  int i = blockIdx.x*256 + threadIdx.x;
  if (i >= n4) return;
  float4 v = ((const float4*)S)[i];
  uint2v o;
  o[0] = pkcvt(v.x, v.y);
  o[1] = pkcvt(v.z, v.w);
  *(uint2v*)&D[i*4] = o;
}

// ---------------- batched weight transposes ----------------
__global__ void k_transW(const float* __restrict__ msg_w1, const float* __restrict__ msg_w2,
                         const float* __restrict__ upd_w1, const float* __restrict__ upd_w2,
                         short* __restrict__ wT){
  int z = blockIdx.z; int l = z/5, w = z%5;
  const float* S;
  switch(w){
    case 0: S = msg_w1 + (size_t)l*513*256; break;
    case 1: S = msg_w1 + (size_t)l*513*256 + 256*256; break;
    case 2: S = msg_w2 + (size_t)l*256*256; break;
    case 3: S = upd_w1 + (size_t)l*256*256; break;
    default: S = upd_w2 + (size_t)l*256*256; break;
  }
  short* D = wT + (size_t)z*65536;
  __shared__ float t[32][33];
  int bx = blockIdx.x*32, by = blockIdx.y*32;
  int lx = threadIdx.x & 31, ly = threadIdx.x >> 5;
  #pragma unroll
  for(int r=0;r<4;r++){ int k = ly + r*8; t[k][lx] = S[(size_t)(by+k)*256 + bx+lx]; }
  __syncthreads();
  #pragma unroll
  for(int r=0;r<4;r++){
    int n = ly + r*8;
    D[(size_t)(bx+n)*256 + by+lx] = f2bf(t[lx][n]);
  }
}

// ---------------- uw1_ext [n=256][352] bf16, batched over layers ----
__global__ void k_uw1ext(const short* __restrict__ wT, const float* __restrict__ edge_w,
                         const float* __restrict__ edge_b, short* __restrict__ uw1ext4){
  int n = blockIdx.x, l = blockIdx.y, tid = threadIdx.x;
  const short* uw1T = wT + (size_t)(l*5+3)*65536;
  short* dst = uw1ext4 + (size_t)l*256*352 + (size_t)n*352;
  dst[tid] = uw1T[(size_t)n*256 + tid];
  if (tid < 96){
    int c = tid;
    float s = 0.f;
    if (c < 64){
      const float* er = edge_w + (size_t)l*64*256 + (size_t)c*256;
      for(int m=0;m<256;m++) s += bf2f(uw1T[(size_t)n*256+m])*er[m];
    } else if (c == 64){
      const float* er = edge_b + (size_t)l*256;
      for(int m=0;m<256;m++) s += bf2f(uw1T[(size_t)n*256+m])*er[m];
    }
    dst[256 + c] = f2bf(s);
  }
}

// ---------------- biasm accumulation, batched over layers ----------------
__global__ void k_biasm_acc(const float* __restrict__ node_b, const float* __restrict__ msg_w1,
                            const float* __restrict__ msg_b1, float* __restrict__ biasm4){
  int j = threadIdx.x;
  int b = blockIdx.x, l = blockIdx.y;
  const float* nb  = node_b + l*256;
  const float* w1  = msg_w1 + (size_t)l*513*256;
  float* biasm = biasm4 + l*256;
  if (b == 16){ atomicAdd(&biasm[j], msg_b1[l*256+j]); return; }
  float s = 0.f;
  for(int k = b*16; k < b*16+16; k++)
    s += nb[k]*(w1[(size_t)k*256+j] + w1[(size_t)(256+k)*256+j]);
  atomicAdd(&biasm[j], s);
}

// ---------------- biasm += ub2_{l-1} @ (Wa_l + Wb_l) ----------------
__global__ void k_biasfold(const float* __restrict__ upd_b2, const short* __restrict__ WabT4,
                           float* __restrict__ biasm4){
  int l = blockIdx.x + 1;
  int j = threadIdx.x;
  const float* ub2 = upd_b2 + (size_t)(l-1)*256;
  const short* W = WabT4 + (size_t)l*131072;
  float s = 0.f;
  for(int k=0;k<256;k++)
    s += ub2[k]*(bf2f(W[(size_t)j*256+k]) + bf2f(W[(size_t)(256+j)*256+k]));
  biasm4[l*256 + j] += s;
}

// ---------------- 32-row bf16 MFMA GEMM (weight prep) ------
template<int K_REAL, int K_LDS, int OBF16>
__global__ __launch_bounds__(256)
void k_gemm_mfma(const short* __restrict__ A, const short* __restrict__ BT,
                 short* __restrict__ Cb, int M, int Nld,
                 int AzStr, int BzStr, int CzStr){
  __shared__ __align__(16) short As[32][K_LDS];
  const int CHL = K_LDS/8, CH = K_REAL/8;
  int tid = threadIdx.x;
  int zz = blockIdx.z;
  const short* Ab = A + (size_t)zz*AzStr;
  BT += (size_t)zz*BzStr;
  int m0 = blockIdx.y*32, n0 = blockIdx.x*256;
  for(int c = tid; c < 32*CHL; c += 256){
    int row = c / CHL, ch = c % CHL;
    uint4v v = (uint4v){0u,0u,0u,0u};
    if (ch < CH) v = *(const uint4v*)&Ab[(size_t)(m0+row)*K_REAL + ch*8];
    *(uint4v*)&As[row][(ch ^ (row&7))*8] = v;
  }
  __syncthreads();
  int wid = tid>>6, lane = tid&63, l15 = lane&15, lq = lane>>4;
  int ncol0 = n0 + wid*64;
  f32x4 acc[2][4];
  #pragma unroll
  for(int mt=0;mt<2;mt++)
    #pragma unroll
    for(int nt=0;nt<4;nt++) acc[mt][nt] = (f32x4){0.f,0.f,0.f,0.f};
  for(int k0=0;k0<K_REAL;k0+=32){
    int kc = k0 + 8*lq;
    short8 a[2], b[4];
    #pragma unroll
    for(int mt=0;mt<2;mt++){
      int row = mt*16 + l15;
      a[mt] = *(const short8*)&As[row][kc ^ ((row&7)<<3)];
    }
    #pragma unroll
    for(int nt=0;nt<4;nt++){
      int col = ncol0 + nt*16 + l15;
      b[nt] = *(const short8*)&BT[(size_t)col*K_REAL + kc];
    }
    #pragma unroll
    for(int mt=0;mt<2;mt++)
      #pragma unroll
      for(int nt=0;nt<4;nt++)
        acc[mt][nt] = __builtin_amdgcn_mfma_f32_16x16x32_bf16(a[mt], b[nt], acc[mt][nt], 0, 0, 0);
  }
  #pragma unroll
  for(int mt=0;mt<2;mt++){
    #pragma unroll
    for(int nt=0;nt<4;nt++){
      int col = ncol0 + nt*16 + l15;
      unsigned w01 = pkcvt(acc[mt][nt][0], acc[mt][nt][1]);
      unsigned w23 = pkcvt(acc[mt][nt][2], acc[mt][nt][3]);
      size_t base = (size_t)zz*CzStr + (size_t)(m0 + mt*16 + lq*4)*Nld + col;
      Cb[base]          = (short)(w01 & 0xFFFF);
      Cb[base +   Nld]  = (short)(w01>>16);
      Cb[base + 2*Nld]  = (short)(w23 & 0xFFFF);
      Cb[base + 3*Nld]  = (short)(w23>>16);
    }
  }
}

// ---------------- 64-row bf16 MFMA GEMM (big M GEMMs; row guards) ------
template<int K_REAL, int K_LDS, int AF32, int AEXT, int BIAS, int ACT, int OF32, int OBF16>
__global__ __launch_bounds__(256)
void k_gemm64(const void* __restrict__ A, const float* __restrict__ A2,
              const short* __restrict__ BT,
              const float* __restrict__ bias, float* __restrict__ Cf,
              short* __restrict__ Cb, int M, int Nld){
  __shared__ __align__(16) short As[64][K_LDS];
  const int CHL = K_LDS/8, CH = K_REAL/8;
  int tid = threadIdx.x;
  const short* Ab = (const short*)A;
  const float* Af = (const float*)A;
  int m0 = blockIdx.y*64, n0 = blockIdx.x*256;
  for(int c = tid; c < 64*CHL; c += 256){
    int row = c / CHL, ch = c % CHL;
    uint4v v = (uint4v){0u,0u,0u,0u};
    int grow = m0 + row;
    if (grow < M){
      if (AEXT){
        if (ch < 32){
          float4 f0 = *(const float4*)&Af[(size_t)grow*256 + ch*8];
          float4 f1 = *(const float4*)&Af[(size_t)grow*256 + ch*8 + 4];
          v[0]=pkcvt(f0.x,f0.y); v[1]=pkcvt(f0.z,f0.w); v[2]=pkcvt(f1.x,f1.y); v[3]=pkcvt(f1.z,f1.w);
        } else if (ch < 44){
          float4 f0 = *(const float4*)&A2[(size_t)grow*96 + (ch-32)*8];
          float4 f1 = *(const float4*)&A2[(size_t)grow*96 + (ch-32)*8 + 4];
          v[0]=pkcvt(f0.x,f0.y); v[1]=pkcvt(f0.z,f0.w); v[2]=pkcvt(f1.x,f1.y); v[3]=pkcvt(f1.z,f1.w);
        }
      } else if (ch < CH) {
        if (AF32){
          float4 f0 = *(const float4*)&Af[(size_t)grow*K_REAL + ch*8];
          float4 f1 = *(const float4*)&Af[(size_t)grow*K_REAL + ch*8 + 4];
          v[0]=pkcvt(f0.x,f0.y); v[1]=pkcvt(f0.z,f0.w); v[2]=pkcvt(f1.x,f1.y); v[3]=pkcvt(f1.z,f1.w);
        } else {
          v = *(const uint4v*)&Ab[(size_t)grow*K_REAL + ch*8];
        }
      }
    }
    *(uint4v*)&As[row][(ch ^ (row&7))*8] = v;
  }
  __syncthreads();
  int wid = tid>>6, lane = tid&63, l15 = lane&15, lq = lane>>4;
  int ncol0 = n0 + wid*64;
  f32x4 acc[4][4];
  #pragma unroll
  for(int mt=0;mt<4;mt++)
    #pragma unroll
    for(int nt=0;nt<4;nt++) acc[mt][nt] = (f32x4){0.f,0.f,0.f,0.f};
  for(int k0=0;k0<K_REAL;k0+=32){
    int kc = k0 + 8*lq;
    short8 a[4], b[4];
    #pragma unroll
    for(int mt=0;mt<4;mt++){
      int row = mt*16 + l15;
      a[mt] = *(const short8*)&As[row][kc ^ ((row&7)<<3)];
    }
    #pragma unroll
    for(int nt=0;nt<4;nt++){
      int col = ncol0 + nt*16 + l15;
      b[nt] = *(const short8*)&BT[(size_t)col*K_REAL + kc];
    }
    #pragma unroll
    for(int mt=0;mt<4;mt++)
      #pragma unroll
      for(int nt=0;nt<4;nt++)
        acc[mt][nt] = __builtin_amdgcn_mfma_f32_16x16x32_bf16(a[mt], b[nt], acc[mt][nt], 0, 0, 0);
  }
  #pragma unroll
  for(int mt=0;mt<4;mt++){
    int row0 = m0 + mt*16 + lq*4;
    if (row0 >= M) continue;
    #pragma unroll
    for(int nt=0;nt<4;nt++){
      int col = ncol0 + nt*16 + l15;
      float bb = BIAS ? bias[col] : 0.f;
      float vv[4];
      #pragma unroll
      for(int r=0;r<4;r++){
        float v = acc[mt][nt][r] + bb;
        if (ACT) v = silu_f(v);
        vv[r] = v;
      }
      if (OF32){
        #pragma unroll
        for(int r=0;r<4;r++)
          if (row0 + r < M)
            Cf[(size_t)(row0+r)*Nld + col] = vv[r];
      }
      if (OBF16){
        unsigned w01 = pkcvt(vv[0], vv[1]);
        unsigned w23 = pkcvt(vv[2], vv[3]);
        short ss[4] = {(short)(w01&0xFFFF),(short)(w01>>16),(short)(w23&0xFFFF),(short)(w23>>16)};
        #pragma unroll
        for(int r=0;r<4;r++)
          if (row0 + r < M)
            Cb[(size_t)(row0+r)*Nld + col] = ss[r];
      }
    }
  }
}

// ---------------- fused upd1 + t_ab-fold ----
__global__ __launch_bounds__(256)
void k_updfold(const float* __restrict__ aggr, const float* __restrict__ EA,
               const short* __restrict__ uw1ext, const float* __restrict__ ub1,
               const short* __restrict__ WfoldT, short* __restrict__ t_ab, int M)
{
  __shared__ __align__(16) short lds[64*384];
  short (*As)[384] = (short(*)[384])lds;
  short (*hh)[256] = (short(*)[256])lds;
  int tid = threadIdx.x;
  int m0 = blockIdx.y*64;
  for(int c = tid; c < 64*48; c += 256){
    int row = c / 48, ch = c % 48;
    uint4v v = (uint4v){0u,0u,0u,0u};
    int grow = m0 + row;
    if (grow < M){
      if (ch < 32){
        float4 f0 = *(const float4*)&aggr[(size_t)grow*256 + ch*8];
        float4 f1 = *(const float4*)&aggr[(size_t)grow*256 + ch*8 + 4];
        v[0]=pkcvt(f0.x,f0.y); v[1]=pkcvt(f0.z,f0.w); v[2]=pkcvt(f1.x,f1.y); v[3]=pkcvt(f1.z,f1.w);
      } else if (ch < 44){
        float4 f0 = *(const float4*)&EA[(size_t)grow*96 + (ch-32)*8];
        float4 f1 = *(const float4*)&EA[(size_t)grow*96 + (ch-32)*8 + 4];
        v[0]=pkcvt(f0.x,f0.y); v[1]=pkcvt(f0.z,f0.w); v[2]=pkcvt(f1.x,f1.y); v[3]=pkcvt(f1.z,f1.w);
      }
    }
    *(uint4v*)&As[row][(ch ^ (row&7))*8] = v;
  }
  __syncthreads();
  int wid = tid>>6, lane = tid&63, l15 = lane&15, lq = lane>>4;
  int ncol1 = wid*64;
  f32x4 acc1[4][4];
  #pragma unroll
  for(int mt=0;mt<4;mt++)
    #pragma unroll
    for(int nt=0;nt<4;nt++) acc1[mt][nt] = (f32x4){0.f,0.f,0.f,0.f};
  for(int k0=0;k0<352;k0+=32){
    int kc = k0 + 8*lq;
    short8 a[4], b[4];
    #pragma unroll
    for(int mt=0;mt<4;mt++){
      int row = mt*16 + l15;
      a[mt] = *(const short8*)&As[row][kc ^ ((row&7)<<3)];
    }
    #pragma unroll
    for(int nt=0;nt<4;nt++){
      int col = ncol1 + nt*16 + l15;
      b[nt] = *(const short8*)&uw1ext[(size_t)col*352 + kc];
    }
    #pragma unroll
    for(int mt=0;mt<4;mt++)
      #pragma unroll
      for(int nt=0;nt<4;nt++)
        acc1[mt][nt] = __builtin_amdgcn_mfma_f32_16x16x32_bf16(a[mt], b[nt], acc1[mt][nt], 0, 0, 0);
  }
  __syncthreads();
  #pragma unroll
  for(int mt=0;mt<4;mt++){
    #pragma unroll
    for(int nt=0;nt<4;nt++){
      int col = ncol1 + nt*16 + l15;
      float bb = ub1[col];
      unsigned w01 = pkcvt(silu_f(acc1[mt][nt][0] + bb), silu_f(acc1[mt][nt][1] + bb));
      unsigned w23 = pkcvt(silu_f(acc1[mt][nt][2] + bb), silu_f(acc1[mt][nt][3] + bb));
      short ss[4] = {(short)(w01&0xFFFF),(short)(w01>>16),(short)(w23&0xFFFF),(short)(w23>>16)};
      #pragma unroll
      for(int r=0;r<4;r++){
        int row = mt*16 + lq*4 + r;
        hh[row][((col>>3) ^ (row&7))*8 + (col&7)] = ss[r];
      }
    }
  }
  __syncthreads();
  #pragma unroll
  for(int hf=0; hf<2; hf++){
    int ncol2 = wid*128 + hf*64;
    f32x4 acc2[4][4];
    #pragma unroll
    for(int mt=0;mt<4;mt++)
      #pragma unroll
      for(int nt=0;nt<4;nt++) acc2[mt][nt] = (f32x4){0.f,0.f,0.f,0.f};
    for(int k0=0;k0<256;k0+=32){
      int kc = k0 + 8*lq;
      short8 a[4], b[4];
      #pragma unroll
      for(int mt=0;mt<4;mt++){
        int row = mt*16 + l15;
        a[mt] = *(const short8*)&hh[row][kc ^ ((row&7)<<3)];
      }
      #pragma unroll
      for(int nt=0;nt<4;nt++){
        int col = ncol2 + nt*16 + l15;
        b[nt] = *(const short8*)&WfoldT[(size_t)col*256 + kc];
      }
      #pragma unroll
      for(int mt=0;mt<4;mt++)
        #pragma unroll
        for(int nt=0;nt<4;nt++)
          acc2[mt][nt] = __builtin_amdgcn_mfma_f32_16x16x32_bf16(a[mt], b[nt], acc2[mt][nt], 0, 0, 0);
    }
    #pragma unroll
    for(int mt=0;mt<4;mt++){
      int row0 = m0 + mt*16 + lq*4;
      if (row0 >= M) continue;
      #pragma unroll
      for(int nt=0;nt<4;nt++){
        int col = ncol2 + nt*16 + l15;
        unsigned w01 = pkcvt(acc2[mt][nt][0], acc2[mt][nt][1]);
        unsigned w23 = pkcvt(acc2[mt][nt][2], acc2[mt][nt][3]);
        short ss[4] = {(short)(w01&0xFFFF),(short)(w01>>16),(short)(w23&0xFFFF),(short)(w23>>16)};
        #pragma unroll
        for(int r=0;r<4;r++)
          if (row0 + r < M)
            t_ab[(size_t)(row0+r)*512 + col] = ss[r];
      }
    }
  }
}

// ---------------- fused edge kernel: persistent grid-stride blocks ----------------
__global__ __launch_bounds__(256)
void k_edge_mfma(const short* __restrict__ t_ab,
                 const float* __restrict__ dist_s,
                 const int* __restrict__ src_s, const int* __restrict__ dst_s,
                 const float* __restrict__ w1c, const float* __restrict__ biasm,
                 const short* __restrict__ w2T, const float* __restrict__ b2,
                 float* __restrict__ aggr)
{
  __shared__ __align__(16) unsigned char ulds[256*34*2];
  short (*h)[256] = (short(*)[256])ulds;
  short* outl = (short*)ulds;
  __shared__ int sdst[32], ssrc[32];
  __shared__ float sdist[32];
  int tid = threadIdx.x;
  int wid = tid>>6, lane = tid&63;
  int half = lane>>5, cl = lane&31;
  int l15 = lane & 15, lq = lane >> 4;
  int nb = wid*64;

  // loop-invariant per-column vectors (hoisted across tiles)
  float wc8[8], bm8[8];
  {
    float4 w0 = *(const float4*)&w1c[8*cl], w1v = *(const float4*)&w1c[8*cl+4];
    float4 b0 = *(const float4*)&biasm[8*cl], b1v = *(const float4*)&biasm[8*cl+4];
    wc8[0]=w0.x; wc8[1]=w0.y; wc8[2]=w0.z; wc8[3]=w0.w;
    wc8[4]=w1v.x; wc8[5]=w1v.y; wc8[6]=w1v.z; wc8[7]=w1v.w;
    bm8[0]=b0.x; bm8[1]=b0.y; bm8[2]=b0.z; bm8[3]=b0.w;
    bm8[4]=b1v.x; bm8[5]=b1v.y; bm8[6]=b1v.z; bm8[7]=b1v.w;
  }
  float bb_ep = b2[nb + ( (tid>>2) & 63 )]; (void)bb_ep; // (unused helper removed)

  for(int tile = blockIdx.x; tile < EDGE_TILES; tile += gridDim.x){
    int e0 = tile*32;
    if (tid < 32){
      sdst[tid] = dst_s[e0 + tid];
      ssrc[tid] = src_s[e0 + tid];
      sdist[tid] = dist_s[e0 + tid];
    }
    __syncthreads();

    #pragma unroll
    for(int p=0;p<4;p++){
      int e = wid*8 + p*2 + half;
      int d = sdst[e], s = ssrc[e];
      float de = sdist[e];
      short8 va = *(const short8*)&t_ab[(size_t)d*512 + 8*cl];
      short8 vb = *(const short8*)&t_ab[(size_t)s*512 + 256 + 8*cl];
      float f[8];
      #pragma unroll
      for(int i=0;i<8;i++)
        f[i] = silu_f(bf2f(va[i]) + bf2f(vb[i]) + de*wc8[i] + bm8[i]);
      uint4v hv;
      hv[0]=pkcvt(f[0],f[1]); hv[1]=pkcvt(f[2],f[3]); hv[2]=pkcvt(f[4],f[5]); hv[3]=pkcvt(f[6],f[7]);
      *(uint4v*)&h[e][(8*cl) ^ ((e&7)<<3)] = hv;
    }
    __syncthreads();

    f32x4 acc[2][4];
    #pragma unroll
    for(int mt=0;mt<2;mt++)
      #pragma unroll
      for(int nt=0;nt<4;nt++) acc[mt][nt] = (f32x4){0.f,0.f,0.f,0.f};

    for(int k0=0;k0<256;k0+=32){
      int kc = k0 + 8*lq;
      short8 a[2], b[4];
      #pragma unroll
      for(int mt=0;mt<2;mt++){
        int row = mt*16 + l15;
        a[mt] = *(const short8*)&h[row][kc ^ ((row&7)<<3)];
      }
      #pragma unroll
      for(int nt=0;nt<4;nt++){
        int col = nb + nt*16 + l15;
        b[nt] = *(const short8*)&w2T[(size_t)col*256 + kc];
      }
      #pragma unroll
      for(int mt=0;mt<2;mt++)
        #pragma unroll
        for(int nt=0;nt<4;nt++)
          acc[mt][nt] = __builtin_amdgcn_mfma_f32_16x16x32_bf16(a[mt], b[nt], acc[mt][nt], 0, 0, 0);
    }
    __syncthreads();

    #pragma unroll
    for(int mt=0;mt<2;mt++){
      #pragma unroll
      for(int nt=0;nt<4;nt++){
        int col = nb + nt*16 + l15;
        float bb = b2[col];
        float s0 = silu_f(acc[mt][nt][0] + bb);
        float s1 = silu_f(acc[mt][nt][1] + bb);
        float s2 = silu_f(acc[mt][nt][2] + bb);
        float s3 = silu_f(acc[mt][nt][3] + bb);
        unsigned* d32 = (unsigned*)&outl[col*34 + mt*16 + lq*4];
        d32[0] = pkcvt(s0, s1);
        d32[1] = pkcvt(s2, s3);
      }
    }
    __syncthreads();

    int j = tid;
    float accu = 0.f;
    int prev = sdst[0];
    #pragma unroll
    for(int e2=0;e2<32;e2+=2){
      unsigned w = *(const unsigned*)&outl[j*34 + e2];
      int d0 = sdst[e2], d1 = sdst[e2+1];
      if (d0 != prev){
        atomicAdd(&aggr[(size_t)prev*256 + j], accu);
        accu = 0.f; prev = d0;
      }
      accu += bf_lo(w);
      if (d1 != prev){
        atomicAdd(&aggr[(size_t)prev*256 + j], accu);
        accu = 0.f; prev = d1;
      }
      accu += bf_hi(w);
    }
    atomicAdd(&aggr[(size_t)prev*256 + j], accu);
    __syncthreads();   // sdst stable until all threads done scanning
  }
}

// ---------------- batch-segmented pooling ----------------
__global__ void k_ghist(const int* __restrict__ batch, int* __restrict__ gcnt){
  int n = blockIdx.x*256 + threadIdx.x;
  if (n >= N_NODES) return;
  atomicAdd(&gcnt[batch[n]], 1);
}
__global__ void k_gscan(const int* __restrict__ gcnt, int* __restrict__ gptr){
  if (threadIdx.x == 0){
    int s = 0;
    for(int g=0; g<NGRAPH; g++){ gptr[g]=s; s += gcnt[g]; }
    gptr[NGRAPH] = s;
  }
}
__global__ void k_pool_seg(const float* __restrict__ x, const int* __restrict__ gptr,
                           float* __restrict__ pooled){
  int g = blockIdx.x, j = threadIdx.x;
  int b = gptr[g], e = gptr[g+1];
  float s = 0.f;
  for(int n=b; n<e; n++) s += x[(size_t)n*256 + j];
  pooled[g*256 + j] = s;
}

// ---------------- head ----------------
__global__ void k_head(const float* __restrict__ pooled, const float* __restrict__ fw1,
                       const float* __restrict__ fb1, const float* __restrict__ fw2,
                       const float* __restrict__ fb2, float* __restrict__ out){
  __shared__ float red[256];
  int g = blockIdx.x, j = threadIdx.x;
  float s = fb1[j];
  const float* p = &pooled[g*256];
  for(int k=0;k<256;k++) s += p[k]*fw1[k*256+j];
  float hv = silu_f(s)*fw2[j];
  red[j]=hv; __syncthreads();
  for(int off=128;off>0;off>>=1){ if(j<off) red[j]+=red[j+off]; __syncthreads(); }
  if(j==0) out[g] = red[0] + fb2[0];
}

extern "C" void kernel_launch(void* const* d_in, const int* in_sizes, int n_in,
                              void* d_out, int out_size, void* d_ws, size_t ws_size,
                              hipStream_t stream) {
  const float* x_in      = (const float*)d_in[0];
  const float* edge_attr = (const float*)d_in[1];
  const float* pos       = (const float*)d_in[2];
  const int*   ei        = (const int*)d_in[3];
  const int*   batch     = (const int*)d_in[4];
  const float* node_w    = (const float*)d_in[5];
  const float* node_b    = (const float*)d_in[6];
  const float* edge_w    = (const float*)d_in[7];
  const float* edge_b    = (const float*)d_in[8];
  const float* msg_w1    = (const float*)d_in[9];
  const float* msg_b1    = (const float*)d_in[10];
  const float* msg_w2    = (const float*)d_in[11];
  const float* msg_b2    = (const float*)d_in[12];
  const float* upd_w1    = (const float*)d_in[13];
  const float* upd_b1    = (const float*)d_in[14];
  const float* upd_w2    = (const float*)d_in[15];
  const float* upd_b2    = (const float*)d_in[16];
  const float* fc_w1     = (const float*)d_in[17];
  const float* fc_b1     = (const float*)d_in[18];
  const float* fc_w2     = (const float*)d_in[19];
  const float* fc_b2     = (const float*)d_in[20];
  float* out = (float*)d_out;

  float* ws = (float*)d_ws;
  int* cnt     = (int*)ws; ws += N_NODES;
  int* off     = (int*)ws; ws += N_NODES;
  int* row_ptr = (int*)ws; ws += N_NODES+4;
  int* src_s   = (int*)ws; ws += N_EDGES;
  int* dst_s   = (int*)ws; ws += N_EDGES;
  int* eid_s   = (int*)ws; ws += N_EDGES;
  float* dist_s= ws; ws += N_EDGES;
  int* gcnt    = (int*)ws; ws += NGRAPH;
  int* gptr    = (int*)ws; ws += NGRAPH+4;
  short* wT      = (short*)ws; ws += 20*65536/2;
  short* nw_bf4  = (short*)ws; ws += 4*65536/2;
  short* uw2_bf4 = (short*)ws; ws += 4*65536/2;
  short* uw1ext4 = (short*)ws; ws += 4*256*352/2 + 64;
  short* WabT4   = (short*)ws; ws += 4*131072/2;
  short* WfoldT4 = (short*)ws; ws += 3*131072/2;
  float* biasm4  = ws; ws += 4*256;
  short* h_bf   = (short*)ws; ws += (size_t)N_NODES*256/2;
  float* EA_aug = ws; ws += (size_t)N_NODES*96;
  float* tabreg = ws; ws += (size_t)N_NODES*256;
  float* aggr   = ws; ws += (size_t)N_NODES*256;
  float* pooled = ws; ws += NGRAPH*256;

  short* t_ab   = (short*)tabreg;
  float* xfinal = aggr;

  hipMemsetAsync(cnt, 0, N_NODES*sizeof(int), stream);
  k_hist<<<(N_EDGES+255)/256, 256, 0, stream>>>(ei, cnt);
  k_scan<<<1, 256, 0, stream>>>(cnt, row_ptr, off);
  k_scatter<<<(N_EDGES+255)/256, 256, 0, stream>>>(ei, off, src_s, dst_s, eid_s);
  k_dist_s<<<(N_EDGES+255)/256, 256, 0, stream>>>(src_s, dst_s, pos, dist_s);
  k_eaagg_s<<<N_NODES/4, 256, 0, stream>>>(row_ptr, eid_s, edge_attr, EA_aug);
  hipMemsetAsync(gcnt, 0, NGRAPH*sizeof(int), stream);
  k_ghist<<<(N_NODES+255)/256, 256, 0, stream>>>(batch, gcnt);
  k_gscan<<<1, 64, 0, stream>>>(gcnt, gptr);

  k_transW<<<dim3(8,8,20), 256, 0, stream>>>(msg_w1, msg_w2, upd_w1, upd_w2, wT);
  k_f2b<<<256, 256, 0, stream>>>(node_w, nw_bf4, 4*65536/4);
  k_f2b<<<256, 256, 0, stream>>>(upd_w2, uw2_bf4, 4*65536/4);
  k_uw1ext<<<dim3(256,4), 256, 0, stream>>>(wT, edge_w, edge_b, uw1ext4);
  hipMemsetAsync(biasm4, 0, 4*256*sizeof(float), stream);
  k_biasm_acc<<<dim3(17,4), 256, 0, stream>>>(node_b, msg_w1, msg_b1, biasm4);
  k_gemm_mfma<256,256,1><<<dim3(1,8,4), 256, 0, stream>>>(
      wT,         nw_bf4, WabT4,         256, 256, 5*65536, 65536, 131072);
  k_gemm_mfma<256,256,1><<<dim3(1,8,4), 256, 0, stream>>>(
      wT + 65536, nw_bf4, WabT4 + 65536, 256, 256, 5*65536, 65536, 131072);
  k_gemm_mfma<256,256,1><<<dim3(1,16,3), 256, 0, stream>>>(
      WabT4 + 131072, uw2_bf4, WfoldT4, 512, 256, 131072, 65536, 131072);
  k_biasfold<<<3, 256, 0, stream>>>(upd_b2, WabT4, biasm4);

  k_gemm64<256,256,1,0,0,0,0,1><<<dim3(2,313), 256, 0, stream>>>(
      x_in, nullptr, WabT4, nullptr, nullptr, t_ab, N_NODES, 512);

  for(int l=0;l<4;l++){
    const float* w1  = msg_w1 + (size_t)l*513*256;
    const float* mb2 = msg_b2 + l*256;
    const float* ub1 = upd_b1 + l*256;
    const float* ub2 = upd_b2 + l*256;
    const short* w2T_l  = wT + (size_t)(l*5+2)*65536;
    const short* uw2T_l = wT + (size_t)(l*5+4)*65536;

    hipMemsetAsync(aggr, 0, (size_t)N_NODES*256*sizeof(float), stream);

    k_edge_mfma<<<EDGE_BLOCKS, 256, 0, stream>>>(t_ab, dist_s, src_s, dst_s,
                                                 w1 + 512*256, biasm4 + l*256,
                                                 w2T_l, mb2, aggr);

    if (l < 3){
      k_updfold<<<dim3(1,313), 256, 0, stream>>>(
          aggr, EA_aug, uw1ext4 + (size_t)l*256*352, ub1,
          WfoldT4 + (size_t)l*131072, t_ab, N_NODES);
    } else {
      k_gemm64<352,384,1,1,1,1,0,1><<<dim3(1,313), 256, 0, stream>>>(
          aggr, EA_aug, uw1ext4 + (size_t)l*256*352, ub1, nullptr, h_bf, N_NODES, 256);
      k_gemm64<256,256,0,0,1,0,1,0><<<dim3(1,313), 256, 0, stream>>>(
          h_bf, nullptr, uw2T_l, ub2, xfinal, nullptr, N_NODES, 256);
    }
  }

  k_pool_seg<<<NGRAPH, 256, 0, stream>>>(xfinal, gptr, pooled);
  k_head<<<NGRAPH, 256, 0, stream>>>(pooled, fc_w1, fc_b1, fc_w2, fc_b2, out);
}

// Round 18
// 1249.421 us; speedup vs baseline: 1.0488x; 1.0488x over previous
//
#include <hip/hip_runtime.h>
#include <hip/hip_bf16.h>
#include <math.h>

#define N_NODES 20000
#define N_EDGES 320000
#define NGRAPH 64

typedef __attribute__((ext_vector_type(8))) short short8;
typedef __attribute__((ext_vector_type(4))) short short4x;
typedef __attribute__((ext_vector_type(4))) float f32x4;
typedef __attribute__((ext_vector_type(4))) unsigned uint4v;
typedef __attribute__((ext_vector_type(2))) unsigned uint2v;

// fast silu: hardware v_rcp_f32 instead of IEEE division (~12 inst -> ~2)
__device__ __forceinline__ float silu_f(float v){
  return v * __builtin_amdgcn_rcpf(1.0f + __expf(-v));
}
__device__ __forceinline__ float bf2f(short s){
  unsigned u = ((unsigned)(unsigned short)s) << 16;
  float f; __builtin_memcpy(&f, &u, 4); return f;
}
__device__ __forceinline__ short f2bf(float f){
  unsigned u; __builtin_memcpy(&u, &f, 4);
  unsigned r = (u + 0x7FFFu + ((u >> 16) & 1u)) >> 16;
  return (short)r;
}
__device__ __forceinline__ unsigned pkcvt(float lo, float hi){
  unsigned r;
  asm("v_cvt_pk_bf16_f32 %0, %1, %2" : "=v"(r) : "v"(lo), "v"(hi));
  return r;
}
__device__ __forceinline__ float bf_lo(unsigned w){
  unsigned u = w << 16; float f; __builtin_memcpy(&f, &u, 4); return f;
}
__device__ __forceinline__ float bf_hi(unsigned w){
  unsigned u = w & 0xFFFF0000u; float f; __builtin_memcpy(&f, &u, 4); return f;
}

// ---------------- CSR build: histogram, scan, scatter ----------------
__global__ void k_hist(const int* __restrict__ ei, int* __restrict__ cnt){
  int e = blockIdx.x*256 + threadIdx.x;
  if (e >= N_EDGES) return;
  atomicAdd(&cnt[ei[N_EDGES + e]], 1);
}

__global__ void k_scan(const int* __restrict__ cnt, int* __restrict__ row_ptr,
                       int* __restrict__ off){
  __shared__ int ssum[256];
  int t = threadIdx.x;
  const int CHK = (N_NODES + 255)/256;
  int base = t*CHK;
  int s = 0;
  for(int i=0;i<CHK;i++){ int idx=base+i; if(idx<N_NODES) s += cnt[idx]; }
  ssum[t]=s; __syncthreads();
  for(int o=1;o<256;o<<=1){
    int v = (t>=o)? ssum[t-o] : 0;
    __syncthreads();
    ssum[t] += v;
    __syncthreads();
  }
  int pre = (t==0)? 0 : ssum[t-1];
  for(int i=0;i<CHK;i++){
    int idx=base+i; if(idx>=N_NODES) break;
    row_ptr[idx]=pre; off[idx]=pre; pre += cnt[idx];
  }
  if(t==255) row_ptr[N_NODES]=pre;
}

__global__ void k_scatter(const int* __restrict__ ei, int* __restrict__ off,
                          int* __restrict__ src_s, int* __restrict__ dst_s,
                          int* __restrict__ eid_s){
  int e = blockIdx.x*256 + threadIdx.x;
  if (e >= N_EDGES) return;
  int d = ei[N_EDGES + e];
  int p = atomicAdd(&off[d], 1);
  dst_s[p]=d; src_s[p]=ei[e]; eid_s[p]=e;
}

// ---------------- edge distance (sorted order) ----------------
__global__ void k_dist_s(const int* __restrict__ src_s, const int* __restrict__ dst_s,
                         const float* __restrict__ pos, float* __restrict__ dist_s){
  int i = blockIdx.x*256 + threadIdx.x;
  if (i >= N_EDGES) return;
  int s = src_s[i], d = dst_s[i];
  float dx = pos[s*3+0]-pos[d*3+0];
  float dy = pos[s*3+1]-pos[d*3+1];
  float dz = pos[s*3+2]-pos[d*3+2];
  dist_s[i] = sqrtf(dx*dx+dy*dy+dz*dz);
}

// ---------------- EA_aug via CSR: per-dst sum of edge_attr, count, zeros (stride 96) ----
__global__ void k_eaagg_s(const int* __restrict__ row_ptr, const int* __restrict__ eid_s,
                          const float* __restrict__ edge_attr, float* __restrict__ EA){
  int sub = threadIdx.x>>6, j = threadIdx.x&63;
  int d = blockIdx.x*4 + sub;
  if (d >= N_NODES) return;
  int b = row_ptr[d], e = row_ptr[d+1];
  float s = 0.f;
  for(int i=b;i<e;i++) s += edge_attr[(size_t)eid_s[i]*64 + j];
  EA[(size_t)d*96 + j] = s;
  if (j < 32) EA[(size_t)d*96 + 64 + j] = (j==0) ? (float)(e-b) : 0.f;
}

// ---------------- fp32 -> bf16 convert ----------------
__global__ void k_f2b(const float* __restrict__ S, short* __restrict__ D, int n4){
  int i = blockIdx.x*256 + threadIdx.x;
  if (i >= n4) return;
  float4 v = ((const float4*)S)[i];
  uint2v o;
  o[0] = pkcvt(v.x, v.y);
  o[1] = pkcvt(v.z, v.w);
  *(uint2v*)&D[i*4] = o;
}

// ---------------- batched weight transposes: z = l*5 + which, fp32[256][256] -> bf16 [n][k] ----
__global__ void k_transW(const float* __restrict__ msg_w1, const float* __restrict__ msg_w2,
                         const float* __restrict__ upd_w1, const float* __restrict__ upd_w2,
                         short* __restrict__ wT){
  int z = blockIdx.z; int l = z/5, w = z%5;
  const float* S;
  switch(w){
    case 0: S = msg_w1 + (size_t)l*513*256; break;
    case 1: S = msg_w1 + (size_t)l*513*256 + 256*256; break;
    case 2: S = msg_w2 + (size_t)l*256*256; break;
    case 3: S = upd_w1 + (size_t)l*256*256; break;
    default: S = upd_w2 + (size_t)l*256*256; break;
  }
  short* D = wT + (size_t)z*65536;
  __shared__ float t[32][33];
  int bx = blockIdx.x*32, by = blockIdx.y*32;
  int lx = threadIdx.x & 31, ly = threadIdx.x >> 5;
  #pragma unroll
  for(int r=0;r<4;r++){ int k = ly + r*8; t[k][lx] = S[(size_t)(by+k)*256 + bx+lx]; }
  __syncthreads();
  #pragma unroll
  for(int r=0;r<4;r++){
    int n = ly + r*8;
    D[(size_t)(bx+n)*256 + by+lx] = f2bf(t[lx][n]);
  }
}

// ---------------- uw1_ext [n=256][352] bf16, batched over layers (blockIdx.y=l) ----
__global__ void k_uw1ext(const short* __restrict__ wT, const float* __restrict__ edge_w,
                         const float* __restrict__ edge_b, short* __restrict__ uw1ext4){
  int n = blockIdx.x, l = blockIdx.y, tid = threadIdx.x;
  const short* uw1T = wT + (size_t)(l*5+3)*65536;
  short* dst = uw1ext4 + (size_t)l*256*352 + (size_t)n*352;
  dst[tid] = uw1T[(size_t)n*256 + tid];
  if (tid < 96){
    int c = tid;
    float s = 0.f;
    if (c < 64){
      const float* er = edge_w + (size_t)l*64*256 + (size_t)c*256;
      for(int m=0;m<256;m++) s += bf2f(uw1T[(size_t)n*256+m])*er[m];
    } else if (c == 64){
      const float* er = edge_b + (size_t)l*256;
      for(int m=0;m<256;m++) s += bf2f(uw1T[(size_t)n*256+m])*er[m];
    }
    dst[256 + c] = f2bf(s);
  }
}

// ---------------- biasm accumulation, batched over layers (blockIdx.y=l) ----------------
__global__ void k_biasm_acc(const float* __restrict__ node_b, const float* __restrict__ msg_w1,
                            const float* __restrict__ msg_b1, float* __restrict__ biasm4){
  int j = threadIdx.x;
  int b = blockIdx.x, l = blockIdx.y;
  const float* nb  = node_b + l*256;
  const float* w1  = msg_w1 + (size_t)l*513*256;
  float* biasm = biasm4 + l*256;
  if (b == 16){ atomicAdd(&biasm[j], msg_b1[l*256+j]); return; }
  float s = 0.f;
  for(int k = b*16; k < b*16+16; k++)
    s += nb[k]*(w1[(size_t)k*256+j] + w1[(size_t)(256+k)*256+j]);
  atomicAdd(&biasm[j], s);
}

// ---------------- biasm += ub2_{l-1} @ (Wa_l + Wb_l), l = blockIdx.x+1 ----------------
__global__ void k_biasfold(const float* __restrict__ upd_b2, const short* __restrict__ WabT4,
                           float* __restrict__ biasm4){
  int l = blockIdx.x + 1;           // 1..3
  int j = threadIdx.x;
  const float* ub2 = upd_b2 + (size_t)(l-1)*256;
  const short* W = WabT4 + (size_t)l*131072;
  float s = 0.f;
  for(int k=0;k<256;k++)
    s += ub2[k]*(bf2f(W[(size_t)j*256+k]) + bf2f(W[(size_t)(256+j)*256+k]));
  biasm4[l*256 + j] += s;
}

// ---------------- 32-row bf16 MFMA GEMM (weight prep) ------
template<int K_REAL, int K_LDS, int OBF16>
__global__ __launch_bounds__(256)
void k_gemm_mfma(const short* __restrict__ A, const short* __restrict__ BT,
                 short* __restrict__ Cb, int M, int Nld,
                 int AzStr, int BzStr, int CzStr){
  __shared__ __align__(16) short As[32][K_LDS];
  const int CHL = K_LDS/8, CH = K_REAL/8;
  int tid = threadIdx.x;
  int zz = blockIdx.z;
  const short* Ab = A + (size_t)zz*AzStr;
  BT += (size_t)zz*BzStr;
  int m0 = blockIdx.y*32, n0 = blockIdx.x*256;
  for(int c = tid; c < 32*CHL; c += 256){
    int row = c / CHL, ch = c % CHL;
    uint4v v = (uint4v){0u,0u,0u,0u};
    if (ch < CH) v = *(const uint4v*)&Ab[(size_t)(m0+row)*K_REAL + ch*8];
    *(uint4v*)&As[row][(ch ^ (row&7))*8] = v;
  }
  __syncthreads();
  int wid = tid>>6, lane = tid&63, l15 = lane&15, lq = lane>>4;
  int ncol0 = n0 + wid*64;
  f32x4 acc[2][4];
  #pragma unroll
  for(int mt=0;mt<2;mt++)
    #pragma unroll
    for(int nt=0;nt<4;nt++) acc[mt][nt] = (f32x4){0.f,0.f,0.f,0.f};
  for(int k0=0;k0<K_REAL;k0+=32){
    int kc = k0 + 8*lq;
    short8 a[2], b[4];
    #pragma unroll
    for(int mt=0;mt<2;mt++){
      int row = mt*16 + l15;
      a[mt] = *(const short8*)&As[row][kc ^ ((row&7)<<3)];
    }
    #pragma unroll
    for(int nt=0;nt<4;nt++){
      int col = ncol0 + nt*16 + l15;
      b[nt] = *(const short8*)&BT[(size_t)col*K_REAL + kc];
    }
    #pragma unroll
    for(int mt=0;mt<2;mt++)
      #pragma unroll
      for(int nt=0;nt<4;nt++)
        acc[mt][nt] = __builtin_amdgcn_mfma_f32_16x16x32_bf16(a[mt], b[nt], acc[mt][nt], 0, 0, 0);
  }
  #pragma unroll
  for(int mt=0;mt<2;mt++){
    #pragma unroll
    for(int nt=0;nt<4;nt++){
      int col = ncol0 + nt*16 + l15;
      unsigned w01 = pkcvt(acc[mt][nt][0], acc[mt][nt][1]);
      unsigned w23 = pkcvt(acc[mt][nt][2], acc[mt][nt][3]);
      size_t base = (size_t)zz*CzStr + (size_t)(m0 + mt*16 + lq*4)*Nld + col;
      Cb[base]          = (short)(w01 & 0xFFFF);
      Cb[base +   Nld]  = (short)(w01>>16);
      Cb[base + 2*Nld]  = (short)(w23 & 0xFFFF);
      Cb[base + 3*Nld]  = (short)(w23>>16);
    }
  }
}

// ---------------- 64-row bf16 MFMA GEMM (big M GEMMs; row guards) ------
template<int K_REAL, int K_LDS, int AF32, int AEXT, int BIAS, int ACT, int OF32, int OBF16>
__global__ __launch_bounds__(256)
void k_gemm64(const void* __restrict__ A, const float* __restrict__ A2,
              const short* __restrict__ BT,
              const float* __restrict__ bias, float* __restrict__ Cf,
              short* __restrict__ Cb, int M, int Nld){
  __shared__ __align__(16) short As[64][K_LDS];
  const int CHL = K_LDS/8, CH = K_REAL/8;
  int tid = threadIdx.x;
  const short* Ab = (const short*)A;
  const float* Af = (const float*)A;
  int m0 = blockIdx.y*64, n0 = blockIdx.x*256;
  for(int c = tid; c < 64*CHL; c += 256){
    int row = c / CHL, ch = c % CHL;
    uint4v v = (uint4v){0u,0u,0u,0u};
    int grow = m0 + row;
    if (grow < M){
      if (AEXT){
        if (ch < 32){
          float4 f0 = *(const float4*)&Af[(size_t)grow*256 + ch*8];
          float4 f1 = *(const float4*)&Af[(size_t)grow*256 + ch*8 + 4];
          v[0]=pkcvt(f0.x,f0.y); v[1]=pkcvt(f0.z,f0.w); v[2]=pkcvt(f1.x,f1.y); v[3]=pkcvt(f1.z,f1.w);
        } else if (ch < 44){
          float4 f0 = *(const float4*)&A2[(size_t)grow*96 + (ch-32)*8];
          float4 f1 = *(const float4*)&A2[(size_t)grow*96 + (ch-32)*8 + 4];
          v[0]=pkcvt(f0.x,f0.y); v[1]=pkcvt(f0.z,f0.w); v[2]=pkcvt(f1.x,f1.y); v[3]=pkcvt(f1.z,f1.w);
        }
      } else if (ch < CH) {
        if (AF32){
          float4 f0 = *(const float4*)&Af[(size_t)grow*K_REAL + ch*8];
          float4 f1 = *(const float4*)&Af[(size_t)grow*K_REAL + ch*8 + 4];
          v[0]=pkcvt(f0.x,f0.y); v[1]=pkcvt(f0.z,f0.w); v[2]=pkcvt(f1.x,f1.y); v[3]=pkcvt(f1.z,f1.w);
        } else {
          v = *(const uint4v*)&Ab[(size_t)grow*K_REAL + ch*8];
        }
      }
    }
    *(uint4v*)&As[row][(ch ^ (row&7))*8] = v;
  }
  __syncthreads();
  int wid = tid>>6, lane = tid&63, l15 = lane&15, lq = lane>>4;
  int ncol0 = n0 + wid*64;
  f32x4 acc[4][4];
  #pragma unroll
  for(int mt=0;mt<4;mt++)
    #pragma unroll
    for(int nt=0;nt<4;nt++) acc[mt][nt] = (f32x4){0.f,0.f,0.f,0.f};
  for(int k0=0;k0<K_REAL;k0+=32){
    int kc = k0 + 8*lq;
    short8 a[4], b[4];
    #pragma unroll
    for(int mt=0;mt<4;mt++){
      int row = mt*16 + l15;
      a[mt] = *(const short8*)&As[row][kc ^ ((row&7)<<3)];
    }
    #pragma unroll
    for(int nt=0;nt<4;nt++){
      int col = ncol0 + nt*16 + l15;
      b[nt] = *(const short8*)&BT[(size_t)col*K_REAL + kc];
    }
    #pragma unroll
    for(int mt=0;mt<4;mt++)
      #pragma unroll
      for(int nt=0;nt<4;nt++)
        acc[mt][nt] = __builtin_amdgcn_mfma_f32_16x16x32_bf16(a[mt], b[nt], acc[mt][nt], 0, 0, 0);
  }
  #pragma unroll
  for(int mt=0;mt<4;mt++){
    int row0 = m0 + mt*16 + lq*4;
    if (row0 >= M) continue;
    #pragma unroll
    for(int nt=0;nt<4;nt++){
      int col = ncol0 + nt*16 + l15;
      float bb = BIAS ? bias[col] : 0.f;
      float vv[4];
      #pragma unroll
      for(int r=0;r<4;r++){
        float v = acc[mt][nt][r] + bb;
        if (ACT) v = silu_f(v);
        vv[r] = v;
      }
      if (OF32){
        #pragma unroll
        for(int r=0;r<4;r++)
          if (row0 + r < M)
            Cf[(size_t)(row0+r)*Nld + col] = vv[r];
      }
      if (OBF16){
        unsigned w01 = pkcvt(vv[0], vv[1]);
        unsigned w23 = pkcvt(vv[2], vv[3]);
        short ss[4] = {(short)(w01&0xFFFF),(short)(w01>>16),(short)(w23&0xFFFF),(short)(w23>>16)};
        #pragma unroll
        for(int r=0;r<4;r++)
          if (row0 + r < M)
            Cb[(size_t)(row0+r)*Nld + col] = ss[r];
      }
    }
  }
}

// ---------------- fused upd1 + t_ab-fold: t_ab = silu([aggr|EA]@uw1ext+ub1) @ WfoldT ----
__global__ __launch_bounds__(256)
void k_updfold(const float* __restrict__ aggr, const float* __restrict__ EA,
               const short* __restrict__ uw1ext, const float* __restrict__ ub1,
               const short* __restrict__ WfoldT, short* __restrict__ t_ab, int M)
{
  __shared__ __align__(16) short lds[64*384];       // 48KB
  short (*As)[384] = (short(*)[384])lds;
  short (*hh)[256] = (short(*)[256])lds;
  int tid = threadIdx.x;
  int m0 = blockIdx.y*64;
  for(int c = tid; c < 64*48; c += 256){
    int row = c / 48, ch = c % 48;
    uint4v v = (uint4v){0u,0u,0u,0u};
    int grow = m0 + row;
    if (grow < M){
      if (ch < 32){
        float4 f0 = *(const float4*)&aggr[(size_t)grow*256 + ch*8];
        float4 f1 = *(const float4*)&aggr[(size_t)grow*256 + ch*8 + 4];
        v[0]=pkcvt(f0.x,f0.y); v[1]=pkcvt(f0.z,f0.w); v[2]=pkcvt(f1.x,f1.y); v[3]=pkcvt(f1.z,f1.w);
      } else if (ch < 44){
        float4 f0 = *(const float4*)&EA[(size_t)grow*96 + (ch-32)*8];
        float4 f1 = *(const float4*)&EA[(size_t)grow*96 + (ch-32)*8 + 4];
        v[0]=pkcvt(f0.x,f0.y); v[1]=pkcvt(f0.z,f0.w); v[2]=pkcvt(f1.x,f1.y); v[3]=pkcvt(f1.z,f1.w);
      }
    }
    *(uint4v*)&As[row][(ch ^ (row&7))*8] = v;
  }
  __syncthreads();
  int wid = tid>>6, lane = tid&63, l15 = lane&15, lq = lane>>4;
  int ncol1 = wid*64;
  f32x4 acc1[4][4];
  #pragma unroll
  for(int mt=0;mt<4;mt++)
    #pragma unroll
    for(int nt=0;nt<4;nt++) acc1[mt][nt] = (f32x4){0.f,0.f,0.f,0.f};
  for(int k0=0;k0<352;k0+=32){
    int kc = k0 + 8*lq;
    short8 a[4], b[4];
    #pragma unroll
    for(int mt=0;mt<4;mt++){
      int row = mt*16 + l15;
      a[mt] = *(const short8*)&As[row][kc ^ ((row&7)<<3)];
    }
    #pragma unroll
    for(int nt=0;nt<4;nt++){
      int col = ncol1 + nt*16 + l15;
      b[nt] = *(const short8*)&uw1ext[(size_t)col*352 + kc];
    }
    #pragma unroll
    for(int mt=0;mt<4;mt++)
      #pragma unroll
      for(int nt=0;nt<4;nt++)
        acc1[mt][nt] = __builtin_amdgcn_mfma_f32_16x16x32_bf16(a[mt], b[nt], acc1[mt][nt], 0, 0, 0);
  }
  __syncthreads();
  #pragma unroll
  for(int mt=0;mt<4;mt++){
    #pragma unroll
    for(int nt=0;nt<4;nt++){
      int col = ncol1 + nt*16 + l15;
      float bb = ub1[col];
      unsigned w01 = pkcvt(silu_f(acc1[mt][nt][0] + bb), silu_f(acc1[mt][nt][1] + bb));
      unsigned w23 = pkcvt(silu_f(acc1[mt][nt][2] + bb), silu_f(acc1[mt][nt][3] + bb));
      short ss[4] = {(short)(w01&0xFFFF),(short)(w01>>16),(short)(w23&0xFFFF),(short)(w23>>16)};
      #pragma unroll
      for(int r=0;r<4;r++){
        int row = mt*16 + lq*4 + r;
        hh[row][((col>>3) ^ (row&7))*8 + (col&7)] = ss[r];
      }
    }
  }
  __syncthreads();
  #pragma unroll
  for(int hf=0; hf<2; hf++){
    int ncol2 = wid*128 + hf*64;
    f32x4 acc2[4][4];
    #pragma unroll
    for(int mt=0;mt<4;mt++)
      #pragma unroll
      for(int nt=0;nt<4;nt++) acc2[mt][nt] = (f32x4){0.f,0.f,0.f,0.f};
    for(int k0=0;k0<256;k0+=32){
      int kc = k0 + 8*lq;
      short8 a[4], b[4];
      #pragma unroll
      for(int mt=0;mt<4;mt++){
        int row = mt*16 + l15;
        a[mt] = *(const short8*)&hh[row][kc ^ ((row&7)<<3)];
      }
      #pragma unroll
      for(int nt=0;nt<4;nt++){
        int col = ncol2 + nt*16 + l15;
        b[nt] = *(const short8*)&WfoldT[(size_t)col*256 + kc];
      }
      #pragma unroll
      for(int mt=0;mt<4;mt++)
        #pragma unroll
        for(int nt=0;nt<4;nt++)
          acc2[mt][nt] = __builtin_amdgcn_mfma_f32_16x16x32_bf16(a[mt], b[nt], acc2[mt][nt], 0, 0, 0);
    }
    #pragma unroll
    for(int mt=0;mt<4;mt++){
      int row0 = m0 + mt*16 + lq*4;
      if (row0 >= M) continue;
      #pragma unroll
      for(int nt=0;nt<4;nt++){
        int col = ncol2 + nt*16 + l15;
        unsigned w01 = pkcvt(acc2[mt][nt][0], acc2[mt][nt][1]);
        unsigned w23 = pkcvt(acc2[mt][nt][2], acc2[mt][nt][3]);
        short ss[4] = {(short)(w01&0xFFFF),(short)(w01>>16),(short)(w23&0xFFFF),(short)(w23>>16)};
        #pragma unroll
        for(int r=0;r<4;r++)
          if (row0 + r < M)
            t_ab[(size_t)(row0+r)*512 + col] = ss[r];
      }
    }
  }
}

// ---------------- fused edge kernel (MFMA + bf16 single-pass segmented reduce) ----------------
__global__ __launch_bounds__(256)
void k_edge_mfma(const short* __restrict__ t_ab,
                 const float* __restrict__ dist_s,
                 const int* __restrict__ src_s, const int* __restrict__ dst_s,
                 const float* __restrict__ w1c, const float* __restrict__ biasm,
                 const short* __restrict__ w2T, const float* __restrict__ b2,
                 float* __restrict__ aggr)
{
  __shared__ __align__(16) unsigned char ulds[256*34*2];
  short (*h)[256] = (short(*)[256])ulds;
  short* outl = (short*)ulds;
  __shared__ int sdst[32], ssrc[32];
  __shared__ float sdist[32];
  int tid = threadIdx.x;
  int e0 = blockIdx.x*32;
  if (tid < 32){
    sdst[tid] = dst_s[e0 + tid];
    ssrc[tid] = src_s[e0 + tid];
    sdist[tid] = dist_s[e0 + tid];
  }
  __syncthreads();
  int wid = tid>>6, lane = tid&63;
  int half = lane>>5, cl = lane&31;
  float wc8[8], bm8[8];
  {
    float4 w0 = *(const float4*)&w1c[8*cl], w1v = *(const float4*)&w1c[8*cl+4];
    float4 b0 = *(const float4*)&biasm[8*cl], b1v = *(const float4*)&biasm[8*cl+4];
    wc8[0]=w0.x; wc8[1]=w0.y; wc8[2]=w0.z; wc8[3]=w0.w;
    wc8[4]=w1v.x; wc8[5]=w1v.y; wc8[6]=w1v.z; wc8[7]=w1v.w;
    bm8[0]=b0.x; bm8[1]=b0.y; bm8[2]=b0.z; bm8[3]=b0.w;
    bm8[4]=b1v.x; bm8[5]=b1v.y; bm8[6]=b1v.z; bm8[7]=b1v.w;
  }
  #pragma unroll
  for(int p=0;p<4;p++){
    int e = wid*8 + p*2 + half;
    int d = sdst[e], s = ssrc[e];
    float de = sdist[e];
    short8 va = *(const short8*)&t_ab[(size_t)d*512 + 8*cl];
    short8 vb = *(const short8*)&t_ab[(size_t)s*512 + 256 + 8*cl];
    float f[8];
    #pragma unroll
    for(int i=0;i<8;i++)
      f[i] = silu_f(bf2f(va[i]) + bf2f(vb[i]) + de*wc8[i] + bm8[i]);
    uint4v hv;
    hv[0]=pkcvt(f[0],f[1]); hv[1]=pkcvt(f[2],f[3]); hv[2]=pkcvt(f[4],f[5]); hv[3]=pkcvt(f[6],f[7]);
    *(uint4v*)&h[e][(8*cl) ^ ((e&7)<<3)] = hv;
  }
  __syncthreads();

  int l15 = lane & 15, lq = lane >> 4;
  int nb = wid*64;
  f32x4 acc[2][4];
  #pragma unroll
  for(int mt=0;mt<2;mt++)
    #pragma unroll
    for(int nt=0;nt<4;nt++) acc[mt][nt] = (f32x4){0.f,0.f,0.f,0.f};

  for(int k0=0;k0<256;k0+=32){
    int kc = k0 + 8*lq;
    short8 a[2], b[4];
    #pragma unroll
    for(int mt=0;mt<2;mt++){
      int row = mt*16 + l15;
      a[mt] = *(const short8*)&h[row][kc ^ ((row&7)<<3)];
    }
    #pragma unroll
    for(int nt=0;nt<4;nt++){
      int col = nb + nt*16 + l15;
      b[nt] = *(const short8*)&w2T[(size_t)col*256 + kc];
    }
    #pragma unroll
    for(int mt=0;mt<2;mt++)
      #pragma unroll
      for(int nt=0;nt<4;nt++)
        acc[mt][nt] = __builtin_amdgcn_mfma_f32_16x16x32_bf16(a[mt], b[nt], acc[mt][nt], 0, 0, 0);
  }
  __syncthreads();

  #pragma unroll
  for(int mt=0;mt<2;mt++){
    #pragma unroll
    for(int nt=0;nt<4;nt++){
      int col = nb + nt*16 + l15;
      float bb = b2[col];
      float s0 = silu_f(acc[mt][nt][0] + bb);
      float s1 = silu_f(acc[mt][nt][1] + bb);
      float s2 = silu_f(acc[mt][nt][2] + bb);
      float s3 = silu_f(acc[mt][nt][3] + bb);
      unsigned* d32 = (unsigned*)&outl[col*34 + mt*16 + lq*4];
      d32[0] = pkcvt(s0, s1);
      d32[1] = pkcvt(s2, s3);
    }
  }
  __syncthreads();

  int j = tid;
  float accu = 0.f;
  int prev = sdst[0];
  #pragma unroll
  for(int e2=0;e2<32;e2+=2){
    unsigned w = *(const unsigned*)&outl[j*34 + e2];
    int d0 = sdst[e2], d1 = sdst[e2+1];
    if (d0 != prev){
      atomicAdd(&aggr[(size_t)prev*256 + j], accu);
      accu = 0.f; prev = d0;
    }
    accu += bf_lo(w);
    if (d1 != prev){
      atomicAdd(&aggr[(size_t)prev*256 + j], accu);
      accu = 0.f; prev = d1;
    }
    accu += bf_hi(w);
  }
  atomicAdd(&aggr[(size_t)prev*256 + j], accu);
}

// ---------------- batch-segmented pooling ----------------
__global__ void k_ghist(const int* __restrict__ batch, int* __restrict__ gcnt){
  int n = blockIdx.x*256 + threadIdx.x;
  if (n >= N_NODES) return;
  atomicAdd(&gcnt[batch[n]], 1);
}
__global__ void k_gscan(const int* __restrict__ gcnt, int* __restrict__ gptr){
  if (threadIdx.x == 0){
    int s = 0;
    for(int g=0; g<NGRAPH; g++){ gptr[g]=s; s += gcnt[g]; }
    gptr[NGRAPH] = s;
  }
}
__global__ void k_pool_seg(const float* __restrict__ x, const int* __restrict__ gptr,
                           float* __restrict__ pooled){
  int g = blockIdx.x, j = threadIdx.x;
  int b = gptr[g], e = gptr[g+1];
  float s = 0.f;
  for(int n=b; n<e; n++) s += x[(size_t)n*256 + j];
  pooled[g*256 + j] = s;
}

// ---------------- head ----------------
__global__ void k_head(const float* __restrict__ pooled, const float* __restrict__ fw1,
                       const float* __restrict__ fb1, const float* __restrict__ fw2,
                       const float* __restrict__ fb2, float* __restrict__ out){
  __shared__ float red[256];
  int g = blockIdx.x, j = threadIdx.x;
  float s = fb1[j];
  const float* p = &pooled[g*256];
  for(int k=0;k<256;k++) s += p[k]*fw1[k*256+j];
  float hv = silu_f(s)*fw2[j];
  red[j]=hv; __syncthreads();
  for(int off=128;off>0;off>>=1){ if(j<off) red[j]+=red[j+off]; __syncthreads(); }
  if(j==0) out[g] = red[0] + fb2[0];
}

extern "C" void kernel_launch(void* const* d_in, const int* in_sizes, int n_in,
                              void* d_out, int out_size, void* d_ws, size_t ws_size,
                              hipStream_t stream) {
  const float* x_in      = (const float*)d_in[0];
  const float* edge_attr = (const float*)d_in[1];
  const float* pos       = (const float*)d_in[2];
  const int*   ei        = (const int*)d_in[3];
  const int*   batch     = (const int*)d_in[4];
  const float* node_w    = (const float*)d_in[5];
  const float* node_b    = (const float*)d_in[6];
  const float* edge_w    = (const float*)d_in[7];
  const float* edge_b    = (const float*)d_in[8];
  const float* msg_w1    = (const float*)d_in[9];
  const float* msg_b1    = (const float*)d_in[10];
  const float* msg_w2    = (const float*)d_in[11];
  const float* msg_b2    = (const float*)d_in[12];
  const float* upd_w1    = (const float*)d_in[13];
  const float* upd_b1    = (const float*)d_in[14];
  const float* upd_w2    = (const float*)d_in[15];
  const float* upd_b2    = (const float*)d_in[16];
  const float* fc_w1     = (const float*)d_in[17];
  const float* fc_b1     = (const float*)d_in[18];
  const float* fc_w2     = (const float*)d_in[19];
  const float* fc_b2     = (const float*)d_in[20];
  float* out = (float*)d_out;

  float* ws = (float*)d_ws;
  int* cnt     = (int*)ws; ws += N_NODES;
  int* off     = (int*)ws; ws += N_NODES;
  int* row_ptr = (int*)ws; ws += N_NODES+4;
  int* src_s   = (int*)ws; ws += N_EDGES;
  int* dst_s   = (int*)ws; ws += N_EDGES;
  int* eid_s   = (int*)ws; ws += N_EDGES;
  float* dist_s= ws; ws += N_EDGES;
  int* gcnt    = (int*)ws; ws += NGRAPH;
  int* gptr    = (int*)ws; ws += NGRAPH+4;
  short* wT      = (short*)ws; ws += 20*65536/2;
  short* nw_bf4  = (short*)ws; ws += 4*65536/2;
  short* uw2_bf4 = (short*)ws; ws += 4*65536/2;
  short* uw1ext4 = (short*)ws; ws += 4*256*352/2 + 64;
  short* WabT4   = (short*)ws; ws += 4*131072/2;
  short* WfoldT4 = (short*)ws; ws += 3*131072/2;
  float* biasm4  = ws; ws += 4*256;
  short* h_bf   = (short*)ws; ws += (size_t)N_NODES*256/2;
  float* EA_aug = ws; ws += (size_t)N_NODES*96;
  float* tabreg = ws; ws += (size_t)N_NODES*256;
  float* aggr   = ws; ws += (size_t)N_NODES*256;
  float* pooled = ws; ws += NGRAPH*256;

  short* t_ab   = (short*)tabreg;
  float* xfinal = aggr;

  hipMemsetAsync(cnt, 0, N_NODES*sizeof(int), stream);
  k_hist<<<(N_EDGES+255)/256, 256, 0, stream>>>(ei, cnt);
  k_scan<<<1, 256, 0, stream>>>(cnt, row_ptr, off);
  k_scatter<<<(N_EDGES+255)/256, 256, 0, stream>>>(ei, off, src_s, dst_s, eid_s);
  k_dist_s<<<(N_EDGES+255)/256, 256, 0, stream>>>(src_s, dst_s, pos, dist_s);
  k_eaagg_s<<<N_NODES/4, 256, 0, stream>>>(row_ptr, eid_s, edge_attr, EA_aug);
  hipMemsetAsync(gcnt, 0, NGRAPH*sizeof(int), stream);
  k_ghist<<<(N_NODES+255)/256, 256, 0, stream>>>(batch, gcnt);
  k_gscan<<<1, 64, 0, stream>>>(gcnt, gptr);

  k_transW<<<dim3(8,8,20), 256, 0, stream>>>(msg_w1, msg_w2, upd_w1, upd_w2, wT);
  k_f2b<<<256, 256, 0, stream>>>(node_w, nw_bf4, 4*65536/4);
  k_f2b<<<256, 256, 0, stream>>>(upd_w2, uw2_bf4, 4*65536/4);
  k_uw1ext<<<dim3(256,4), 256, 0, stream>>>(wT, edge_w, edge_b, uw1ext4);
  hipMemsetAsync(biasm4, 0, 4*256*sizeof(float), stream);
  k_biasm_acc<<<dim3(17,4), 256, 0, stream>>>(node_b, msg_w1, msg_b1, biasm4);
  k_gemm_mfma<256,256,1><<<dim3(1,8,4), 256, 0, stream>>>(
      wT,         nw_bf4, WabT4,         256, 256, 5*65536, 65536, 131072);
  k_gemm_mfma<256,256,1><<<dim3(1,8,4), 256, 0, stream>>>(
      wT + 65536, nw_bf4, WabT4 + 65536, 256, 256, 5*65536, 65536, 131072);
  k_gemm_mfma<256,256,1><<<dim3(1,16,3), 256, 0, stream>>>(
      WabT4 + 131072, uw2_bf4, WfoldT4, 512, 256, 131072, 65536, 131072);
  k_biasfold<<<3, 256, 0, stream>>>(upd_b2, WabT4, biasm4);

  k_gemm64<256,256,1,0,0,0,0,1><<<dim3(2,313), 256, 0, stream>>>(
      x_in, nullptr, WabT4, nullptr, nullptr, t_ab, N_NODES, 512);

  for(int l=0;l<4;l++){
    const float* w1  = msg_w1 + (size_t)l*513*256;
    const float* mb2 = msg_b2 + l*256;
    const float* ub1 = upd_b1 + l*256;
    const float* ub2 = upd_b2 + l*256;
    const short* w2T_l  = wT + (size_t)(l*5+2)*65536;
    const short* uw2T_l = wT + (size_t)(l*5+4)*65536;

    hipMemsetAsync(aggr, 0, (size_t)N_NODES*256*sizeof(float), stream);

    k_edge_mfma<<<N_EDGES/32, 256, 0, stream>>>(t_ab, dist_s, src_s, dst_s,
                                                w1 + 512*256, biasm4 + l*256,
                                                w2T_l, mb2, aggr);

    if (l < 3){
      k_updfold<<<dim3(1,313), 256, 0, stream>>>(
          aggr, EA_aug, uw1ext4 + (size_t)l*256*352, ub1,
          WfoldT4 + (size_t)l*131072, t_ab, N_NODES);
    } else {
      k_gemm64<352,384,1,1,1,1,0,1><<<dim3(1,313), 256, 0, stream>>>(
          aggr, EA_aug, uw1ext4 + (size_t)l*256*352, ub1, nullptr, h_bf, N_NODES, 256);
      k_gemm64<256,256,0,0,1,0,1,0><<<dim3(1,313), 256, 0, stream>>>(
          h_bf, nullptr, uw2T_l, ub2, xfinal, nullptr, N_NODES, 256);
    }
  }

  k_pool_seg<<<NGRAPH, 256, 0, stream>>>(xfinal, gptr, pooled);
  k_head<<<NGRAPH, 256, 0, stream>>>(pooled, fc_w1, fc_b1, fc_w2, fc_b2, out);
}